// Round 1
// baseline (141.331 us; speedup 1.0000x reference)
//
#include <hip/hip_runtime.h>
#include <math.h>

#define N_INW     1024
#define N_DEPTH   8
#define N_GROW    512
#define N_BATCH   4096
#define N_ROWS    4608   // IN_W + 7*GROW — rows ever read
#define N_COL     8      // batch columns per workgroup
#define N_THREADS 512    // 64 blocks * 8 cols

// ---------------- cos/sin table precompute ----------------
__global__ void precompute_cs_kernel(const float* __restrict__ angles,
                                     float2* __restrict__ cs) {
    int i = blockIdx.x * blockDim.x + threadIdx.x;
    if (i < N_DEPTH * 8 * 512) {
        float a = angles[i];
        cs[i] = make_float2(cosf(a), sinf(a));
    }
}

// ---------------- helpers ----------------
template <int S>
__device__ __forceinline__ void rotate_layer(float x[16], const float c[8], const float s[8]) {
#pragma unroll
    for (int j = 0; j < 16; ++j) {
        if ((j & S) == 0) {
            const int jh = j | S;
            const int la = (j / (2 * S)) * S + (j % S);   // compile-time
            float lo = x[j], hi = x[jh];
            x[j]  = c[la] * lo + s[la] * hi;
            x[jh] = c[la] * hi - s[la] * lo;
        }
    }
}

template <bool USE_TABLE>
__device__ __forceinline__ void load_cs(const float2* __restrict__ cs_tab,
                                        const float* __restrict__ angles,
                                        int m, int l, int blk, float c[8], float s[8]) {
    const int base = (m * 8 + l) * 512 + blk * 8;
    if (USE_TABLE) {
        const float4* p = (const float4*)(cs_tab + base);   // 64B contiguous, L2-resident
#pragma unroll
        for (int q = 0; q < 4; ++q) {
            float4 v = p[q];
            c[2 * q]     = v.x; s[2 * q]     = v.y;
            c[2 * q + 1] = v.z; s[2 * q + 1] = v.w;
        }
    } else {
        const float4* p = (const float4*)(angles + base);
        float4 a0 = p[0], a1 = p[1];
        float av[8] = {a0.x, a0.y, a0.z, a0.w, a1.x, a1.y, a1.z, a1.w};
#pragma unroll
        for (int q = 0; q < 8; ++q) __sincosf(av[q], &s[q], &c[q]);
    }
}

// ---------------- fused pipeline ----------------
// One WG = 8 batch columns; whole 4608-row data slab lives in LDS (147456 B -> 1 WG/CU).
// thread t: blk = t>>3 (16-row butterfly block), col = t&7 (local batch column).
template <bool USE_TABLE>
__global__ __launch_bounds__(N_THREADS, 1)
void butterfly_fused_kernel(const float* __restrict__ input,
                            const float* __restrict__ scales,
                            const float* __restrict__ biases,
                            const int*   __restrict__ indices,
                            const float2* __restrict__ cs_tab,
                            const float* __restrict__ angles,
                            float* __restrict__ out) {
    extern __shared__ float lds[];          // [N_ROWS][N_COL], row-major
    const int t   = threadIdx.x;
    const int blk = t >> 3;
    const int col = t & 7;
    const int cg  = blockIdx.x * N_COL + col;   // global batch column

    // init: rows 0..1023 = scales[r] * input[r][cg]
#pragma unroll
    for (int k = 0; k < 16; ++k) {
        const int r = k * 64 + blk;
        lds[r * N_COL + col] = scales[r] * input[r * N_BATCH + cg];
    }
    __syncthreads();

    for (int m = 0; m < N_DEPTH; ++m) {
        // per-block gather indices (contiguous 64B -> int4 x4)
        int idxv[16];
        {
            const int4* ip = (const int4*)(indices + m * N_INW + blk * 16);
#pragma unroll
            for (int q = 0; q < 4; ++q) {
                int4 v = ip[q];
                idxv[4 * q]     = v.x; idxv[4 * q + 1] = v.y;
                idxv[4 * q + 2] = v.z; idxv[4 * q + 3] = v.w;
            }
        }
        float bia[8];
        {
            const float4* bp = (const float4*)(biases + m * N_GROW + blk * 8);
            float4 b0 = bp[0], b1 = bp[1];
            bia[0] = b0.x; bia[1] = b0.y; bia[2] = b0.z; bia[3] = b0.w;
            bia[4] = b1.x; bia[5] = b1.y; bia[6] = b1.z; bia[7] = b1.w;
        }

        // gather 16 rows from LDS
        float x[16];
#pragma unroll
        for (int j = 0; j < 16; ++j) x[j] = lds[idxv[j] * N_COL + col];
        __syncthreads();   // all gathers done before anyone scatters

        float c[8], s[8];
        load_cs<USE_TABLE>(cs_tab, angles, m, 0, blk, c, s); rotate_layer<1>(x, c, s);
        load_cs<USE_TABLE>(cs_tab, angles, m, 1, blk, c, s); rotate_layer<2>(x, c, s);
        load_cs<USE_TABLE>(cs_tab, angles, m, 2, blk, c, s); rotate_layer<4>(x, c, s);
        load_cs<USE_TABLE>(cs_tab, angles, m, 3, blk, c, s); rotate_layer<8>(x, c, s);

        // softplus-like activation on first 8 rows of the block
        float act[8];
#pragma unroll
        for (int j = 0; j < 8; ++j) {
            float pre = x[j] + bia[j];
            float v   = 0.5f * (pre + sqrtf(pre * pre + 1.0f));
            act[j] = v; x[j] = v;
        }

        if (m < N_DEPTH - 1) {
            // append act rows (staggered j by blk: 8-way bank conflict -> free 2-way)
            const int abase = N_INW + m * N_GROW + blk * 8;
#pragma unroll
            for (int jj = 0; jj < 8; ++jj) {
                const int j = (jj + blk) & 7;
                lds[(abase + j) * N_COL + col] = act[j];
            }
            load_cs<USE_TABLE>(cs_tab, angles, m, 4, blk, c, s); rotate_layer<1>(x, c, s);
            load_cs<USE_TABLE>(cs_tab, angles, m, 5, blk, c, s); rotate_layer<2>(x, c, s);
            load_cs<USE_TABLE>(cs_tab, angles, m, 6, blk, c, s); rotate_layer<4>(x, c, s);
            load_cs<USE_TABLE>(cs_tab, angles, m, 7, blk, c, s); rotate_layer<8>(x, c, s);
            // scatter back
#pragma unroll
            for (int j = 0; j < 16; ++j) lds[idxv[j] * N_COL + col] = x[j];
            __syncthreads();   // scatters done before next module's gathers
        } else {
            // module 7: OUT_L rotations + scatter are dead code w.r.t. the output.
            // Output = data[4608:5120] = module-7 activations.
#pragma unroll
            for (int j = 0; j < 8; ++j) out[(blk * 8 + j) * N_BATCH + cg] = act[j];
        }
    }
}

// ---------------- host ----------------
extern "C" void kernel_launch(void* const* d_in, const int* in_sizes, int n_in,
                              void* d_out, int out_size, void* d_ws, size_t ws_size,
                              hipStream_t stream) {
    const float* input   = (const float*)d_in[0];
    const float* scales  = (const float*)d_in[1];
    const float* angles  = (const float*)d_in[2];
    const float* biases  = (const float*)d_in[3];
    const int*   indices = (const int*)d_in[4];
    float* out = (float*)d_out;

    const size_t cs_bytes = (size_t)N_DEPTH * 8 * 512 * sizeof(float2);  // 256 KB
    const size_t lds_bytes = (size_t)N_ROWS * N_COL * sizeof(float);     // 147456 B
    const int grid = N_BATCH / N_COL;                                    // 512 WGs

    if (ws_size >= cs_bytes) {
        float2* cs = (float2*)d_ws;
        precompute_cs_kernel<<<(N_DEPTH * 8 * 512 + 255) / 256, 256, 0, stream>>>(angles, cs);
        butterfly_fused_kernel<true><<<grid, N_THREADS, lds_bytes, stream>>>(
            input, scales, biases, indices, cs, angles, out);
    } else {
        butterfly_fused_kernel<false><<<grid, N_THREADS, lds_bytes, stream>>>(
            input, scales, biases, indices, nullptr, angles, out);
    }
}

// Round 2
// 124.979 us; speedup vs baseline: 1.1308x; 1.1308x over previous
//
#include <hip/hip_runtime.h>
#include <math.h>

#define N_INW     1024
#define N_DEPTH   8
#define N_GROW    512
#define N_BATCH   4096
#define N_ROWS    4608   // IN_W + 7*GROW — rows ever read/written before the output
#define N_COL     4      // batch columns per workgroup (73728 B LDS -> 2 WGs/CU)
#define N_THREADS 256    // 64 butterfly blocks * 4 cols

// ---------------- rotation layer (compile-time stride) ----------------
template <int S>
__device__ __forceinline__ void rotate_layer(float x[16], const float c[8], const float s[8]) {
#pragma unroll
    for (int j = 0; j < 16; ++j) {
        if ((j & S) == 0) {
            const int jh = j | S;
            const int la = (j / (2 * S)) * S + (j % S);   // compile-time
            float lo = x[j], hi = x[jh];
            x[j]  = c[la] * lo + s[la] * hi;
            x[jh] = c[la] * hi - s[la] * lo;
        }
    }
}

// 8 angles for (module m, layer l, block blk) -> c[8], s[8] via HW sincos
__device__ __forceinline__ void make_cs(const float ang[8], float c[8], float s[8]) {
#pragma unroll
    for (int q = 0; q < 8; ++q) __sincosf(ang[q], &s[q], &c[q]);
}

__device__ __forceinline__ void load_idx(const int* __restrict__ indices, int m, int blk,
                                         int idxv[16]) {
    const int4* ip = (const int4*)(indices + m * N_INW + blk * 16);
#pragma unroll
    for (int q = 0; q < 4; ++q) {
        int4 v = ip[q];
        idxv[4 * q] = v.x; idxv[4 * q + 1] = v.y;
        idxv[4 * q + 2] = v.z; idxv[4 * q + 3] = v.w;
    }
}

__device__ __forceinline__ void load_ang(const float* __restrict__ angles, int m, int blk,
                                         float ang[64]) {
#pragma unroll
    for (int l = 0; l < 8; ++l) {
        const float4* p = (const float4*)(angles + (m * 8 + l) * 512 + blk * 8);
        float4 a0 = p[0], a1 = p[1];
        ang[l * 8 + 0] = a0.x; ang[l * 8 + 1] = a0.y; ang[l * 8 + 2] = a0.z; ang[l * 8 + 3] = a0.w;
        ang[l * 8 + 4] = a1.x; ang[l * 8 + 5] = a1.y; ang[l * 8 + 6] = a1.z; ang[l * 8 + 7] = a1.w;
    }
}

__device__ __forceinline__ void load_bias(const float* __restrict__ biases, int m, int blk,
                                          float bia[8]) {
    const float4* bp = (const float4*)(biases + m * N_GROW + blk * 8);
    float4 b0 = bp[0], b1 = bp[1];
    bia[0] = b0.x; bia[1] = b0.y; bia[2] = b0.z; bia[3] = b0.w;
    bia[4] = b1.x; bia[5] = b1.y; bia[6] = b1.z; bia[7] = b1.w;
}

// ---------------- fused pipeline ----------------
// One WG = 4 batch columns; whole 4608-row slab in LDS (73728 B -> 2 WGs/CU so
// barriers only drain half the CU). thread t: blk = t>>2, col = t&3.
// Module loop fully unrolled; module m+1's idx/angles/bias prefetched into
// registers during m's OUT-rotations so the post-barrier gather never waits.
__global__ __launch_bounds__(N_THREADS, 2)
void butterfly_fused_kernel(const float* __restrict__ input,
                            const float* __restrict__ scales,
                            const float* __restrict__ biases,
                            const int*   __restrict__ indices,
                            const float* __restrict__ angles,
                            float* __restrict__ out) {
    extern __shared__ float lds[];          // [N_ROWS][N_COL], row-major
    const int t   = threadIdx.x;
    const int blk = t >> 2;
    const int col = t & 3;
    // XCD swizzle: blocks with blockIdx%8==x own columns [x*512,(x+1)*512) so
    // every 64B input line is consumed within one XCD's L2 (kills 2x over-fetch).
    const int b   = blockIdx.x;
    const int cg  = (((b & 7) * 128) + (b >> 3)) * N_COL + col;  // global batch column

    // prefetch module 0 params
    int   idxv[16];
    float ang[64];
    float bia[8];
    load_idx(indices, 0, blk, idxv);
    load_ang(angles, 0, blk, ang);
    load_bias(biases, 0, blk, bia);

    // init: rows 0..1023 = scales[r] * input[r][cg]
#pragma unroll
    for (int k = 0; k < 16; ++k) {
        const int r = k * 64 + blk;
        lds[r * N_COL + col] = scales[r] * input[r * N_BATCH + cg];
    }
    __syncthreads();

#pragma unroll
    for (int m = 0; m < N_DEPTH; ++m) {
        // gather 16 rows from LDS (idx prefetched -> no vmem wait here)
        float x[16];
#pragma unroll
        for (int j = 0; j < 16; ++j) x[j] = lds[idxv[j] * N_COL + col];
        __syncthreads();   // all gathers done before anyone scatters

        float c[8], s[8];
        make_cs(&ang[0],  c, s); rotate_layer<1>(x, c, s);
        make_cs(&ang[8],  c, s); rotate_layer<2>(x, c, s);
        make_cs(&ang[16], c, s); rotate_layer<4>(x, c, s);
        make_cs(&ang[24], c, s); rotate_layer<8>(x, c, s);

        // softplus-like activation on first 8 rows of the block
        float act[8];
#pragma unroll
        for (int j = 0; j < 8; ++j) {
            float pre = x[j] + bia[j];
            float v   = 0.5f * (pre + sqrtf(pre * pre + 1.0f));
            act[j] = v; x[j] = v;
        }

        if (m < N_DEPTH - 1) {
            // append act rows (j staggered by blk: bank pairs -> free 2-way)
            const int abase = N_INW + m * N_GROW + blk * 8;
#pragma unroll
            for (int jj = 0; jj < 8; ++jj) {
                const int j = (jj + blk) & 7;
                lds[(abase + j) * N_COL + col] = act[j];
            }
            // prefetch module m+1 params into fresh registers; consumers are
            // after the next barrier -> OUT-rotations + scatter hide the latency
            int   idxn[16];
            float angn[64];
            float bian[8];
            load_idx(indices, m + 1, blk, idxn);
            load_ang(angles, m + 1, blk, angn);
            load_bias(biases, m + 1, blk, bian);

            make_cs(&ang[32], c, s); rotate_layer<1>(x, c, s);
            make_cs(&ang[40], c, s); rotate_layer<2>(x, c, s);
            make_cs(&ang[48], c, s); rotate_layer<4>(x, c, s);
            make_cs(&ang[56], c, s); rotate_layer<8>(x, c, s);

            // scatter back
#pragma unroll
            for (int j = 0; j < 16; ++j) lds[idxv[j] * N_COL + col] = x[j];
            __syncthreads();   // scatters done before next module's gathers

            // rotate prefetch buffers into place (register renames after unroll)
#pragma unroll
            for (int q = 0; q < 16; ++q) idxv[q] = idxn[q];
#pragma unroll
            for (int q = 0; q < 64; ++q) ang[q] = angn[q];
#pragma unroll
            for (int q = 0; q < 8; ++q) bia[q] = bian[q];
        } else {
            // module 7: OUT_L rotations + scatter are dead code w.r.t. output.
            // Output = data[4608:5120] = module-7 activations.
#pragma unroll
            for (int j = 0; j < 8; ++j) out[(blk * 8 + j) * N_BATCH + cg] = act[j];
        }
    }
}

// ---------------- host ----------------
extern "C" void kernel_launch(void* const* d_in, const int* in_sizes, int n_in,
                              void* d_out, int out_size, void* d_ws, size_t ws_size,
                              hipStream_t stream) {
    const float* input   = (const float*)d_in[0];
    const float* scales  = (const float*)d_in[1];
    const float* angles  = (const float*)d_in[2];
    const float* biases  = (const float*)d_in[3];
    const int*   indices = (const int*)d_in[4];
    float* out = (float*)d_out;

    const size_t lds_bytes = (size_t)N_ROWS * N_COL * sizeof(float);  // 73728 B
    const int grid = N_BATCH / N_COL;                                 // 1024 WGs

    butterfly_fused_kernel<<<grid, N_THREADS, lds_bytes, stream>>>(
        input, scales, biases, indices, angles, out);
}

// Round 3
// 123.887 us; speedup vs baseline: 1.1408x; 1.0088x over previous
//
#include <hip/hip_runtime.h>
#include <math.h>

#define N_INW     1024
#define N_DEPTH   8
#define N_GROW    512
#define N_BATCH   4096
#define N_ROWS    4608   // IN_W + 7*GROW — rows ever read/written before the output
#define N_COL     4      // batch columns per workgroup (73728 B LDS -> 2 WGs/CU)
#define N_THREADS 256    // 64 butterfly blocks * 4 cols
#define N_LAYERS  64     // DEPTH*8 table layers (last 4 never used, but valid memory)

// ---------------- cos/sin table precompute (once, trivial) ----------------
__global__ void precompute_cs_kernel(const float* __restrict__ angles,
                                     float2* __restrict__ cs) {
    int i = blockIdx.x * blockDim.x + threadIdx.x;
    if (i < N_LAYERS * 512) {
        float a = angles[i];
        cs[i] = make_float2(cosf(a), sinf(a));
    }
}

// ---------------- per-layer cs register buffer ----------------
// v[q] = (c[2q], s[2q], c[2q+1], s[2q+1])
struct CS { float4 v[4]; };

template <bool USE_TABLE>
__device__ __forceinline__ void load_layer(const float4* __restrict__ cs_tab,
                                           const float* __restrict__ angles,
                                           int g, int blk, CS& b) {
    if (USE_TABLE) {
        const float4* p = cs_tab + (g * 512 + blk * 8) / 2;   // float4 = 2 (c,s) pairs
        b.v[0] = p[0]; b.v[1] = p[1]; b.v[2] = p[2]; b.v[3] = p[3];
    } else {
        const float4* p = (const float4*)(angles + g * 512 + blk * 8);
        float4 a0 = p[0], a1 = p[1];
        float av[8] = {a0.x, a0.y, a0.z, a0.w, a1.x, a1.y, a1.z, a1.w};
        float c[8], s[8];
#pragma unroll
        for (int q = 0; q < 8; ++q) __sincosf(av[q], &s[q], &c[q]);
#pragma unroll
        for (int q = 0; q < 4; ++q)
            b.v[q] = make_float4(c[2 * q], s[2 * q], c[2 * q + 1], s[2 * q + 1]);
    }
}

// ---------------- rotation layer (compile-time stride) ----------------
template <int S>
__device__ __forceinline__ void rotate_cs(float x[16], const CS& b) {
    float c[8], s[8];
#pragma unroll
    for (int q = 0; q < 4; ++q) {
        c[2 * q]     = b.v[q].x; s[2 * q]     = b.v[q].y;
        c[2 * q + 1] = b.v[q].z; s[2 * q + 1] = b.v[q].w;
    }
#pragma unroll
    for (int j = 0; j < 16; ++j) {
        if ((j & S) == 0) {
            const int jh = j | S;
            const int la = (j / (2 * S)) * S + (j % S);   // compile-time
            float lo = x[j], hi = x[jh];
            x[j]  = c[la] * lo + s[la] * hi;
            x[jh] = c[la] * hi - s[la] * lo;
        }
    }
}

// Bank swizzle: element offset of (row r, local col c) is r*4 + ((c + (r>>3)) & 3).
// bank = (4*(r&7) + (c + (r>>3))&3) & 31 is a bijection of r mod 32 per col-class:
// 16 random gather rows spread over 32 banks instead of 8 -> <=2-way (free).
__device__ __forceinline__ int lds_byte_addr(int r, int c) {
    return (r * 4 + ((c + (r >> 3)) & 3)) * 4;
}

// per-module gather/scatter byte addresses (swizzle folded in, computed once)
__device__ __forceinline__ void make_addr(const int* __restrict__ indices, int m, int blk,
                                          int col, int addrv[16]) {
    const int4* ip = (const int4*)(indices + m * N_INW + blk * 16);
    int idx[16];
#pragma unroll
    for (int q = 0; q < 4; ++q) {
        int4 v = ip[q];
        idx[4 * q] = v.x; idx[4 * q + 1] = v.y;
        idx[4 * q + 2] = v.z; idx[4 * q + 3] = v.w;
    }
#pragma unroll
    for (int j = 0; j < 16; ++j) addrv[j] = lds_byte_addr(idx[j], col);
}

__device__ __forceinline__ void load_bias(const float* __restrict__ biases, int m, int blk,
                                          float bia[8]) {
    const float4* bp = (const float4*)(biases + m * N_GROW + blk * 8);
    float4 b0 = bp[0], b1 = bp[1];
    bia[0] = b0.x; bia[1] = b0.y; bia[2] = b0.z; bia[3] = b0.w;
    bia[4] = b1.x; bia[5] = b1.y; bia[6] = b1.z; bia[7] = b1.w;
}

// ---------------- fused pipeline ----------------
// One WG = 4 batch columns; 4608-row slab in swizzled LDS (73728 B -> 2 WGs/CU).
// thread t: blk = t>>2, col = t&3. Module loop fully unrolled; cs layers loaded
// from the precomputed table 2 layers ahead into 3 rotating register buffers;
// module m+1's gather addresses / bias prefetched during m's OUT phase.
template <bool USE_TABLE>
__global__ __launch_bounds__(N_THREADS, 2)
void butterfly_fused_kernel(const float* __restrict__ input,
                            const float* __restrict__ scales,
                            const float* __restrict__ biases,
                            const int*   __restrict__ indices,
                            const float4* __restrict__ cs_tab,
                            const float* __restrict__ angles,
                            float* __restrict__ out) {
    extern __shared__ float lds[];
    const int t   = threadIdx.x;
    const int blk = t >> 2;
    const int col = t & 3;
    // XCD swizzle: blockIdx%8 == x owns columns [x*512,(x+1)*512) so each 64B
    // input/output line is consumed within one XCD's L2.
    const int b   = blockIdx.x;
    const int cg  = (((b & 7) * 128) + (b >> 3)) * N_COL + col;

    CS csb[3];
    load_layer<USE_TABLE>(cs_tab, angles, 0, blk, csb[0]);
    load_layer<USE_TABLE>(cs_tab, angles, 1, blk, csb[1]);

    int addrv[16];
    float bia[8];
    make_addr(indices, 0, blk, col, addrv);
    load_bias(biases, 0, blk, bia);

    // init: rows 0..1023 = scales[r] * input[r][cg]  (banks: 2-way max = free)
#pragma unroll
    for (int k = 0; k < 16; ++k) {
        const int r = k * 64 + blk;
        *(float*)((char*)lds + lds_byte_addr(r, col)) = scales[r] * input[r * N_BATCH + cg];
    }
    __syncthreads();

#pragma unroll
    for (int m = 0; m < N_DEPTH; ++m) {
        const int g0 = m * 8;
        // gather 16 rows from LDS (addresses precomputed -> no address latency)
        float x[16];
#pragma unroll
        for (int j = 0; j < 16; ++j) x[j] = *(const float*)((const char*)lds + addrv[j]);
        __syncthreads();   // all gathers done before anyone scatters

        load_layer<USE_TABLE>(cs_tab, angles, g0 + 2, blk, csb[(g0 + 2) % 3]);
        rotate_cs<1>(x, csb[g0 % 3]);
        load_layer<USE_TABLE>(cs_tab, angles, g0 + 3, blk, csb[(g0 + 3) % 3]);
        rotate_cs<2>(x, csb[(g0 + 1) % 3]);
        load_layer<USE_TABLE>(cs_tab, angles, g0 + 4, blk, csb[(g0 + 4) % 3]);
        rotate_cs<4>(x, csb[(g0 + 2) % 3]);
        load_layer<USE_TABLE>(cs_tab, angles, g0 + 5, blk, csb[(g0 + 5) % 3]);
        rotate_cs<8>(x, csb[(g0 + 3) % 3]);

        // softplus-like activation on first 8 rows of the block
        float act[8];
#pragma unroll
        for (int j = 0; j < 8; ++j) {
            float pre = x[j] + bia[j];
            float v   = 0.5f * (pre + sqrtf(pre * pre + 1.0f));
            act[j] = v; x[j] = v;
        }

        if (m < N_DEPTH - 1) {
            // append act rows; stagger j by blk so banks are <=2-way (free)
            const int base = N_INW + m * N_GROW + blk * 8;
            const int colp = (col + (base >> 3)) & 3;   // (base+j)>>3 const for j<8
#pragma unroll
            for (int jj = 0; jj < 8; ++jj) {
                const int j = (jj + blk) & 7;
                *(float*)((char*)lds + ((base + j) * 4 + colp) * 4) = act[j];
            }
            // prefetch module m+1 params (consumed after next barrier)
            int addrn[16];
            float bian[8];
            make_addr(indices, m + 1, blk, col, addrn);
            load_bias(biases, m + 1, blk, bian);

            load_layer<USE_TABLE>(cs_tab, angles, g0 + 6, blk, csb[(g0 + 6) % 3]);
            rotate_cs<1>(x, csb[(g0 + 4) % 3]);
            load_layer<USE_TABLE>(cs_tab, angles, g0 + 7, blk, csb[(g0 + 7) % 3]);
            rotate_cs<2>(x, csb[(g0 + 5) % 3]);
            load_layer<USE_TABLE>(cs_tab, angles, g0 + 8, blk, csb[(g0 + 8) % 3]);
            rotate_cs<4>(x, csb[(g0 + 6) % 3]);
            load_layer<USE_TABLE>(cs_tab, angles, g0 + 9, blk, csb[(g0 + 9) % 3]);
            rotate_cs<8>(x, csb[(g0 + 7) % 3]);

            // scatter back (same spread addresses as the gather)
#pragma unroll
            for (int j = 0; j < 16; ++j) *(float*)((char*)lds + addrv[j]) = x[j];
            __syncthreads();

#pragma unroll
            for (int q = 0; q < 16; ++q) addrv[q] = addrn[q];
#pragma unroll
            for (int q = 0; q < 8; ++q) bia[q] = bian[q];
        } else {
            // module 7: OUT rotations + scatter are dead code w.r.t. the output.
#pragma unroll
            for (int j = 0; j < 8; ++j) out[(blk * 8 + j) * N_BATCH + cg] = act[j];
        }
    }
}

// ---------------- host ----------------
extern "C" void kernel_launch(void* const* d_in, const int* in_sizes, int n_in,
                              void* d_out, int out_size, void* d_ws, size_t ws_size,
                              hipStream_t stream) {
    const float* input   = (const float*)d_in[0];
    const float* scales  = (const float*)d_in[1];
    const float* angles  = (const float*)d_in[2];
    const float* biases  = (const float*)d_in[3];
    const int*   indices = (const int*)d_in[4];
    float* out = (float*)d_out;

    const size_t cs_bytes  = (size_t)N_LAYERS * 512 * sizeof(float2);  // 256 KB
    const size_t lds_bytes = (size_t)N_ROWS * N_COL * sizeof(float);   // 73728 B
    const int grid = N_BATCH / N_COL;                                  // 1024 WGs

    if (ws_size >= cs_bytes) {
        precompute_cs_kernel<<<N_LAYERS * 512 / 256, 256, 0, stream>>>(angles, (float2*)d_ws);
        butterfly_fused_kernel<true><<<grid, N_THREADS, lds_bytes, stream>>>(
            input, scales, biases, indices, (const float4*)d_ws, angles, out);
    } else {
        butterfly_fused_kernel<false><<<grid, N_THREADS, lds_bytes, stream>>>(
            input, scales, biases, indices, nullptr, angles, out);
    }
}